// Round 3
// baseline (581.133 us; speedup 1.0000x reference)
//
#include <hip/hip_runtime.h>
#include <hip/hip_bf16.h>
#include <math.h>

#define N_NODES 16384
#define T_TRI   65536
#define H_DIM   128
#define G_POOL  512
#define NITER   4
#define NLAY    4
#define RMAX    (T_TRI + 512)
#define MT      (RMAX / 128)      // 516 tiles of 128 rows

#define INV_STD 0.9999950000374996f

typedef __attribute__((ext_vector_type(8))) short bhalf8;
typedef __attribute__((ext_vector_type(4))) float f32x4;

__device__ __forceinline__ unsigned short f2b(float f) {
    unsigned int u = __float_as_uint(f);
    unsigned int r = (u + 0x7fffu + ((u >> 16) & 1u)) >> 16;
    return (unsigned short)r;
}
__device__ __forceinline__ float b2f(unsigned short b) {
    return __uint_as_float(((unsigned int)b) << 16);
}

// ---------------- group classification / counting sort ----------------

__device__ __forceinline__ int group_of(int eij, int ejk, int nei) {
    return ((eij < nei) ? 0 : 2) + ((ejk < nei) ? 0 : 1);
}

__global__ void hist_k(const int* __restrict__ edxjk, const int* __restrict__ edxij,
                       const int* __restrict__ neip, int* __restrict__ ints) {
    __shared__ int lc[4];
    if (threadIdx.x < 4) lc[threadIdx.x] = 0;
    __syncthreads();
    int t = blockIdx.x * 256 + threadIdx.x;
    int nei = *neip;
    int g = group_of(edxij[t], edxjk[t], nei);
    atomicAdd(&lc[g], 1);
    __syncthreads();
    if (threadIdx.x < 4) atomicAdd(&ints[threadIdx.x], lc[threadIdx.x]);
}

__global__ void offsets_k(int* __restrict__ ints) {
    if (threadIdx.x == 0 && blockIdx.x == 0) {
        int a = 0;
        ints[8] = 0;  // aoff[0]
        for (int g = 0; g < 4; ++g) {
            a = (a + ints[g] + 127) & ~127;
            ints[9 + g] = a;  // aoff[g+1]
        }
    }
}

__global__ void scatter_k(const int* __restrict__ edxjk, const int* __restrict__ edxij,
                          const int* __restrict__ neip, int* __restrict__ ints,
                          int* __restrict__ rowmap) {
    int t = blockIdx.x * 256 + threadIdx.x;
    int nei = *neip;
    int g = group_of(edxij[t], edxjk[t], nei);
    int lane = threadIdx.x & 63;
    unsigned long long msame = 0;
    #pragma unroll
    for (int q = 0; q < 4; ++q) {
        unsigned long long mq = __ballot(g == q);
        if (g == q) msame = mq;
    }
    int leader = __ffsll((long long)msame) - 1;
    int rank = __popcll(msame & ((1ull << lane) - 1ull));
    int base = 0;
    if (lane == leader) base = atomicAdd(&ints[4 + g], __popcll(msame));
    base = __shfl(base, leader);
    int aoffg = ints[8 + g];
    rowmap[aoffg + base + rank] = t;
}

// ---------------- weight prep (fp32 -> bf16, transposed to [n][k]) ----------------

__global__ void prepW0_k(const float* __restrict__ W0, unsigned short* __restrict__ WT0) {
    int idx = blockIdx.x * 256 + threadIdx.x;   // over 16*128*512
    int k = idx & 511;
    int n = (idx >> 9) & 127;
    int ig = idx >> 16;                          // it*4+g
    WT0[idx] = f2b(W0[((size_t)ig * 512 + k) * 128 + n]);
}

__global__ void prepWh_k(const float* __restrict__ Wh, unsigned short* __restrict__ WTh) {
    int idx = blockIdx.x * 256 + threadIdx.x;   // over 64*128*128
    int k = idx & 127;
    int n = (idx >> 7) & 127;
    int ilg = idx >> 14;                         // (it*NL+l)*4+g
    WTh[idx] = f2b(Wh[((size_t)ilg * 128 + k) * 128 + n]);
}

// ---------------- geo encoding ----------------

__global__ void geo_k(const float* __restrict__ pos, const int* __restrict__ eidx,
                      const float* __restrict__ Wg, const float* __restrict__ bg,
                      const float* __restrict__ gamg, const float* __restrict__ betg,
                      unsigned short* __restrict__ geob) {
    int t = blockIdx.x * 2 + (threadIdx.x >> 7);
    int h = threadIdx.x & 127;
    int ni = eidx[t], nj = eidx[T_TRI + t], nk = eidx[2 * T_TRI + t];
    float ix = pos[2 * ni], iy = pos[2 * ni + 1];
    float jx = pos[2 * nj], jy = pos[2 * nj + 1];
    float kx = pos[2 * nk], ky = pos[2 * nk + 1];
    float v1x = jx - ix, v1y = jy - iy;
    float v2x = kx - jx, v2y = ky - jy;
    float dij = sqrtf(v1x * v1x + v1y * v1y);
    float djk = sqrtf(v2x * v2x + v2y * v2y);
    float cr = v1x * v2y - v1y * v2x;
    float dt = v1x * v2x + v1y * v2y;
    float th = atan2f(fabsf(cr), dt);
    float v = dij * Wg[h] + djk * Wg[128 + h] + th * Wg[256 + h] + bg[h];
    v = v * (gamg[h] * INV_STD) + betg[h];
    v = fmaxf(v, 0.0f);
    geob[(size_t)t * 128 + h] = f2b(v);
}

// ---------------- GEMM0: gathered [128rows,512] x [512,128] ----------------

__global__ __launch_bounds__(256) void gemm0_k(
    const unsigned short* __restrict__ nfb, const unsigned short* __restrict__ geob,
    const int* __restrict__ eidx, const int* __restrict__ rowmap,
    const int* __restrict__ aoff, const unsigned short* __restrict__ WT0,
    const float* __restrict__ b0, const float* __restrict__ g0, const float* __restrict__ be0,
    unsigned short* __restrict__ hout, int it) {
    __shared__ unsigned short As[128 * 64];
    __shared__ unsigned short Bs[128 * 64];  // BT[n][k]
    const int r0 = blockIdx.x * 128;
    int g = 0;
    if (r0 >= aoff[1]) g = 1;
    if (r0 >= aoff[2]) g = 2;
    if (r0 >= aoff[3]) g = 3;
    const int tid = threadIdx.x;
    const int lane = tid & 63;
    const int wid = tid >> 6;
    const int wm = wid >> 1, wn = wid & 1;
    const int lr = lane & 15, lq = lane >> 4;
    f32x4 acc[4][4];
    const f32x4 zero = {0.f, 0.f, 0.f, 0.f};
    #pragma unroll
    for (int m = 0; m < 4; ++m)
        #pragma unroll
        for (int n = 0; n < 4; ++n) acc[m][n] = zero;

    const unsigned short* Wt = WT0 + (size_t)(it * 4 + g) * 128 * 512;

    for (int k0 = 0; k0 < 512; k0 += 64) {
        const int region = k0 >> 7;   // 0:nf[i] 1:nf[j] 2:nf[k] 3:geo
        const int half = k0 & 127;    // 0 or 64
        #pragma unroll
        for (int p = 0; p < 4; ++p) {
            int e = p * 2048 + tid * 8;
            int row = e >> 6, col = e & 63;
            int tt = rowmap[r0 + row];
            int4 v = {0, 0, 0, 0};
            if (tt >= 0) {
                const unsigned short* src;
                if (region < 3) src = nfb + (size_t)eidx[region * T_TRI + tt] * 128 + half;
                else src = geob + (size_t)tt * 128 + half;
                v = *reinterpret_cast<const int4*>(src + col);
            }
            *reinterpret_cast<int4*>(&As[row * 64 + (((col >> 3) ^ (row & 7)) << 3)]) = v;
        }
        #pragma unroll
        for (int p = 0; p < 4; ++p) {
            int e = p * 2048 + tid * 8;
            int n = e >> 6, col = e & 63;
            int4 v = *reinterpret_cast<const int4*>(Wt + (size_t)n * 512 + k0 + col);
            *reinterpret_cast<int4*>(&Bs[n * 64 + (((col >> 3) ^ (n & 7)) << 3)]) = v;
        }
        __syncthreads();
        #pragma unroll
        for (int ks = 0; ks < 2; ++ks) {
            bhalf8 af[4], bf[4];
            #pragma unroll
            for (int m = 0; m < 4; ++m) {
                int row = 64 * wm + 16 * m + lr;
                int c8 = (4 * ks + lq) ^ (row & 7);
                af[m] = *reinterpret_cast<const bhalf8*>(&As[row * 64 + (c8 << 3)]);
            }
            #pragma unroll
            for (int n = 0; n < 4; ++n) {
                int nn = 64 * wn + 16 * n + lr;
                int c8 = (4 * ks + lq) ^ (nn & 7);
                bf[n] = *reinterpret_cast<const bhalf8*>(&Bs[nn * 64 + (c8 << 3)]);
            }
            #pragma unroll
            for (int m = 0; m < 4; ++m)
                #pragma unroll
                for (int n = 0; n < 4; ++n)
                    acc[m][n] = __builtin_amdgcn_mfma_f32_16x16x32_bf16(af[m], bf[n], acc[m][n], 0, 0, 0);
        }
        __syncthreads();
    }
    const float* bb = b0 + (it * 4 + g) * 128;
    const float* gg = g0 + (it * 4 + g) * 128;
    const float* be = be0 + (it * 4 + g) * 128;
    #pragma unroll
    for (int n = 0; n < 4; ++n) {
        int col = 64 * wn + 16 * n + lr;
        float sc = gg[col] * INV_STD;
        float bbc = bb[col], bec = be[col];
        #pragma unroll
        for (int m = 0; m < 4; ++m) {
            #pragma unroll
            for (int r = 0; r < 4; ++r) {
                int row = r0 + 64 * wm + 16 * m + lq * 4 + r;
                float v = fmaxf((acc[m][n][r] + bbc) * sc + bec, 0.0f);
                hout[(size_t)row * 128 + col] = f2b(v);
            }
        }
    }
}

// ---------------- hidden GEMM: [128rows,128] x [128,128] (+optional scatter) ----------------

__global__ __launch_bounds__(256) void gemmh_k(
    const unsigned short* __restrict__ hin, const int* __restrict__ rowmap,
    const int* __restrict__ aoff, const unsigned short* __restrict__ WTh,
    const float* __restrict__ bh, const float* __restrict__ gh, const float* __restrict__ beh,
    const float* __restrict__ att, const int* __restrict__ eidx,
    unsigned short* __restrict__ hout, float* __restrict__ nfout,
    int it, int l, int last) {
    __shared__ unsigned short As[128 * 64];
    __shared__ unsigned short Bs[128 * 64];
    const int r0 = blockIdx.x * 128;
    int g = 0;
    if (r0 >= aoff[1]) g = 1;
    if (r0 >= aoff[2]) g = 2;
    if (r0 >= aoff[3]) g = 3;
    const int tid = threadIdx.x;
    const int lane = tid & 63;
    const int wid = tid >> 6;
    const int wm = wid >> 1, wn = wid & 1;
    const int lr = lane & 15, lq = lane >> 4;
    f32x4 acc[4][4];
    const f32x4 zero = {0.f, 0.f, 0.f, 0.f};
    #pragma unroll
    for (int m = 0; m < 4; ++m)
        #pragma unroll
        for (int n = 0; n < 4; ++n) acc[m][n] = zero;

    const int ilg = (it * NLAY + l) * 4 + g;
    const unsigned short* Wt = WTh + (size_t)ilg * 128 * 128;

    for (int k0 = 0; k0 < 128; k0 += 64) {
        #pragma unroll
        for (int p = 0; p < 4; ++p) {
            int e = p * 2048 + tid * 8;
            int row = e >> 6, col = e & 63;
            int4 v = *reinterpret_cast<const int4*>(&hin[(size_t)(r0 + row) * 128 + k0 + col]);
            *reinterpret_cast<int4*>(&As[row * 64 + (((col >> 3) ^ (row & 7)) << 3)]) = v;
        }
        #pragma unroll
        for (int p = 0; p < 4; ++p) {
            int e = p * 2048 + tid * 8;
            int n = e >> 6, col = e & 63;
            int4 v = *reinterpret_cast<const int4*>(Wt + (size_t)n * 128 + k0 + col);
            *reinterpret_cast<int4*>(&Bs[n * 64 + (((col >> 3) ^ (n & 7)) << 3)]) = v;
        }
        __syncthreads();
        #pragma unroll
        for (int ks = 0; ks < 2; ++ks) {
            bhalf8 af[4], bf[4];
            #pragma unroll
            for (int m = 0; m < 4; ++m) {
                int row = 64 * wm + 16 * m + lr;
                int c8 = (4 * ks + lq) ^ (row & 7);
                af[m] = *reinterpret_cast<const bhalf8*>(&As[row * 64 + (c8 << 3)]);
            }
            #pragma unroll
            for (int n = 0; n < 4; ++n) {
                int nn = 64 * wn + 16 * n + lr;
                int c8 = (4 * ks + lq) ^ (nn & 7);
                bf[n] = *reinterpret_cast<const bhalf8*>(&Bs[nn * 64 + (c8 << 3)]);
            }
            #pragma unroll
            for (int m = 0; m < 4; ++m)
                #pragma unroll
                for (int n = 0; n < 4; ++n)
                    acc[m][n] = __builtin_amdgcn_mfma_f32_16x16x32_bf16(af[m], bf[n], acc[m][n], 0, 0, 0);
        }
        __syncthreads();
    }
    const float* bb = bh + (size_t)ilg * 128;
    const float* gg = gh + (size_t)ilg * 128;
    const float* be = beh + (size_t)ilg * 128;
    if (!last) {
        #pragma unroll
        for (int n = 0; n < 4; ++n) {
            int col = 64 * wn + 16 * n + lr;
            float sc = gg[col] * INV_STD;
            float bbc = bb[col], bec = be[col];
            #pragma unroll
            for (int m = 0; m < 4; ++m) {
                #pragma unroll
                for (int r = 0; r < 4; ++r) {
                    int row = r0 + 64 * wm + 16 * m + lq * 4 + r;
                    float v = fmaxf((acc[m][n][r] + bbc) * sc + bec, 0.0f);
                    hout[(size_t)row * 128 + col] = f2b(v);
                }
            }
        }
    } else {
        float attg = att[g];
        float scn[4], bbn[4], ben[4];
        int coln[4];
        #pragma unroll
        for (int n = 0; n < 4; ++n) {
            coln[n] = 64 * wn + 16 * n + lr;
            scn[n] = gg[coln[n]] * INV_STD;
            bbn[n] = bb[coln[n]];
            ben[n] = be[coln[n]];
        }
        #pragma unroll
        for (int m = 0; m < 4; ++m) {
            #pragma unroll
            for (int r = 0; r < 4; ++r) {
                int row = r0 + 64 * wm + 16 * m + lq * 4 + r;
                int tt = rowmap[row];
                if (tt < 0) continue;
                int node = eidx[tt];  // i-index
                #pragma unroll
                for (int n = 0; n < 4; ++n) {
                    float v = fmaxf((acc[m][n][r] + bbn[n]) * scn[n] + ben[n], 0.0f);
                    // leaky_relu of non-negative value is identity; apply att
                    atomicAdd(&nfout[(size_t)node * 128 + coln[n]], v * attg);
                }
            }
        }
    }
}

// ---------------- nf fp32 -> bf16 ----------------

__global__ void cvt_k(const float* __restrict__ src, unsigned short* __restrict__ dst) {
    int i = blockIdx.x * 256 + threadIdx.x;  // over N*128/4
    float4 v = reinterpret_cast<const float4*>(src)[i];
    ushort4 o;
    o.x = f2b(v.x); o.y = f2b(v.y); o.z = f2b(v.z); o.w = f2b(v.w);
    reinterpret_cast<ushort4*>(dst)[i] = o;
}

// ---------------- pool + clamp ----------------

__global__ void pool_k(const float* __restrict__ nf4, const int* __restrict__ ntf,
                       float* __restrict__ emb) {
    int gid = blockIdx.x * 256 + threadIdx.x;  // over N*512
    int n = gid >> 9;
    int c = gid & 511;
    int grp = ntf[n];
    float v = nf4[(size_t)(c >> 7) * N_NODES * 128 + (size_t)n * 128 + (c & 127)];
    atomicAdd(&emb[(size_t)grp * 512 + c], v);
}

__global__ void clamp_k(const float* __restrict__ emb, float* __restrict__ out) {
    int i = blockIdx.x * 256 + threadIdx.x;
    out[i] = fminf(emb[i], 1.0e6f);
}

// ---------------- launch ----------------

extern "C" void kernel_launch(void* const* d_in, const int* in_sizes, int n_in,
                              void* d_out, int out_size, void* d_ws, size_t ws_size,
                              hipStream_t stream) {
    (void)in_sizes; (void)n_in; (void)out_size; (void)ws_size;
    const float* pos   = (const float*)d_in[0];
    const int*   eidx  = (const int*)d_in[1];
    const int*   edxjk = (const int*)d_in[2];
    const int*   edxij = (const int*)d_in[3];
    const int*   neip  = (const int*)d_in[4];
    const int*   ntf   = (const int*)d_in[5];
    const float* Wg    = (const float*)d_in[6];
    const float* bg    = (const float*)d_in[7];
    const float* gamg  = (const float*)d_in[8];
    const float* betg  = (const float*)d_in[9];
    const float* W0    = (const float*)d_in[10];
    const float* b0    = (const float*)d_in[11];
    const float* g0    = (const float*)d_in[12];
    const float* be0   = (const float*)d_in[13];
    const float* Wh    = (const float*)d_in[14];
    const float* bhp   = (const float*)d_in[15];
    const float* ghp   = (const float*)d_in[16];
    const float* behp  = (const float*)d_in[17];
    const float* att   = (const float*)d_in[18];

    char* w = (char*)d_ws;
    size_t off = 0;
    auto alloc = [&](size_t b) -> char* {
        char* p = w + off;
        off += (b + 255) & ~(size_t)255;
        return p;
    };
    int* ints            = (int*)alloc(256);                               // counts[4],cursor[4],aoff[5]
    int* rowmap          = (int*)alloc((size_t)RMAX * 4);
    unsigned short* WT0  = (unsigned short*)alloc((size_t)16 * 128 * 512 * 2);
    unsigned short* WTh  = (unsigned short*)alloc((size_t)64 * 128 * 128 * 2);
    unsigned short* geob = (unsigned short*)alloc((size_t)T_TRI * 128 * 2);
    unsigned short* nfb  = (unsigned short*)alloc((size_t)N_NODES * 128 * 2);
    float* nf4           = (float*)alloc((size_t)4 * N_NODES * 128 * 4);
    unsigned short* hA   = (unsigned short*)alloc((size_t)RMAX * 128 * 2);
    unsigned short* hB   = (unsigned short*)alloc((size_t)RMAX * 128 * 2);
    float* emb           = (float*)alloc((size_t)G_POOL * 512 * 4);

    hipMemsetAsync(ints, 0, 256, stream);
    hipMemsetAsync(rowmap, 0xFF, (size_t)RMAX * 4, stream);
    hipMemsetAsync(nfb, 0, (size_t)N_NODES * 128 * 2, stream);
    hipMemsetAsync(nf4, 0, (size_t)4 * N_NODES * 128 * 4, stream);
    hipMemsetAsync(emb, 0, (size_t)G_POOL * 512 * 4, stream);

    hist_k<<<256, 256, 0, stream>>>(edxjk, edxij, neip, ints);
    offsets_k<<<1, 1, 0, stream>>>(ints);
    scatter_k<<<256, 256, 0, stream>>>(edxjk, edxij, neip, ints, rowmap);
    prepW0_k<<<4096, 256, 0, stream>>>(W0, WT0);
    prepWh_k<<<4096, 256, 0, stream>>>(Wh, WTh);
    geo_k<<<T_TRI / 2, 256, 0, stream>>>(pos, eidx, Wg, bg, gamg, betg, geob);

    for (int it = 0; it < NITER; ++it) {
        gemm0_k<<<MT, 256, 0, stream>>>(nfb, geob, eidx, rowmap, ints + 8, WT0, b0, g0, be0, hA, it);
        gemmh_k<<<MT, 256, 0, stream>>>(hA, rowmap, ints + 8, WTh, bhp, ghp, behp, att, eidx, hB, nullptr, it, 0, 0);
        gemmh_k<<<MT, 256, 0, stream>>>(hB, rowmap, ints + 8, WTh, bhp, ghp, behp, att, eidx, hA, nullptr, it, 1, 0);
        gemmh_k<<<MT, 256, 0, stream>>>(hA, rowmap, ints + 8, WTh, bhp, ghp, behp, att, eidx, hB, nullptr, it, 2, 0);
        gemmh_k<<<MT, 256, 0, stream>>>(hB, rowmap, ints + 8, WTh, bhp, ghp, behp, att, eidx, nullptr,
                                        nf4 + (size_t)it * N_NODES * 128, it, 3, 1);
        cvt_k<<<2048, 256, 0, stream>>>(nf4 + (size_t)it * N_NODES * 128, nfb);
    }

    pool_k<<<32768, 256, 0, stream>>>(nf4, ntf, emb);
    clamp_k<<<1024, 256, 0, stream>>>(emb, (float*)d_out);
}